// Round 7
// baseline (210.712 us; speedup 1.0000x reference)
//
#include <hip/hip_runtime.h>

// Geometry fixed by the reference: x [B=2, C=64, R_rot=6, charts=5, H=128, W=256] fp32.
#define RROT   6
#define CHARTS 5
#define CHART_STRIDE 32768LL                 // H*W = 128*256
#define ROT_STRIDE   163840LL                // 5*CHART_STRIDE
#define BC_STRIDE    983040LL                // 6*ROT_STRIDE

typedef float f4 __attribute__((ext_vector_type(4)));

// R4's pipelined grid-strided streaming copy, with PLAIN (cached) loads and
// stores instead of non-temporal. The fill kernels (plain stores) sustain
// 6.9 TB/s on this chip vs our 5.9 with NT — testing whether NT hints were
// costing the L2 write-merge path. Structure otherwise identical to R4:
// next step's 4 loads issue before current step's 4 stores.
__global__ __launch_bounds__(256) void copy_bulk(const f4* __restrict__ in,
                                                 f4* __restrict__ out,
                                                 long long n4) {
    const int t = threadIdx.x;
    const long long n_steps = n4 >> 10;               // granules / 1024
    const long long G = gridDim.x;
    long long s = blockIdx.x;
    if (s < n_steps) {
        long long b = (s << 10) + t;
        f4 a0 = in[b];
        f4 a1 = in[b + 256];
        f4 a2 = in[b + 512];
        f4 a3 = in[b + 768];
        for (;;) {
            long long s2 = s + G;
            if (s2 < n_steps) {
                long long b2 = (s2 << 10) + t;
                f4 c0 = in[b2];
                f4 c1 = in[b2 + 256];
                f4 c2 = in[b2 + 512];
                f4 c3 = in[b2 + 768];
                out[b]       = a0;
                out[b + 256] = a1;
                out[b + 512] = a2;
                out[b + 768] = a3;
                a0 = c0; a1 = c1; a2 = c2; a3 = c3;
                s = s2; b = b2;
            } else {
                out[b]       = a0;
                out[b + 256] = a1;
                out[b + 512] = a2;
                out[b + 768] = a3;
                break;
            }
        }
    }
    // Tail (n4 % 1024) — empty for this shape, kept for safety.
    long long tail = n_steps << 10;
    long long stride = G * blockDim.x;
    for (long long g = tail + (long long)blockIdx.x * blockDim.x + t; g < n4; g += stride)
        out[g] = in[g];
}

// One thread per (bc, chart): compute both pole means (6 rot x 5 neighbors)
// from the INPUT and overwrite the 12 pole entries in out. Stream-ordered
// after the copy, so the overwrite is race-free.
__global__ void pole_fix(const float* __restrict__ x,
                         float* __restrict__ out, int total) {
    int idx = blockIdx.x * blockDim.x + threadIdx.x;
    if (idx >= total) return;
    int c  = idx % CHARTS;
    int bc = idx / CHARTS;
    int cm = (c + CHARTS - 1) % CHARTS;

    const float* base = x + (long long)bc * BC_STRIDE;

    // V1 neighbors of pole (0,0): [c,1,0],[c,1,1],[c,0,1],[cm,127,128],[cm,127,127]
    const long long off1[5] = {
        c  * CHART_STRIDE + 256, c * CHART_STRIDE + 257, c * CHART_STRIDE + 1,
        cm * CHART_STRIDE + 32640, cm * CHART_STRIDE + 32639,
    };
    // V2 neighbors of pole (0,128): [c,1,128],[c,1,129],[c,0,129],[cm,127,255],[c,0,127]
    const long long off2[5] = {
        c  * CHART_STRIDE + 384, c * CHART_STRIDE + 385, c * CHART_STRIDE + 129,
        cm * CHART_STRIDE + 32767, c * CHART_STRIDE + 127,
    };

    float s1 = 0.0f, s2 = 0.0f;
    #pragma unroll
    for (int r = 0; r < RROT; ++r) {
        const float* rb = base + r * ROT_STRIDE;
        #pragma unroll
        for (int n = 0; n < 5; ++n) {
            s1 += rb[off1[n]];
            s2 += rb[off2[n]];
        }
    }
    float m1 = s1 * (1.0f / 30.0f);
    float m2 = s2 * (1.0f / 30.0f);

    float* obase = out + (long long)bc * BC_STRIDE + (long long)c * CHART_STRIDE;
    #pragma unroll
    for (int r = 0; r < RROT; ++r) {
        obase[r * ROT_STRIDE + 0]   = m1;
        obase[r * ROT_STRIDE + 128] = m2;
    }
}

extern "C" void kernel_launch(void* const* d_in, const int* in_sizes, int n_in,
                              void* d_out, int out_size, void* d_ws, size_t ws_size,
                              hipStream_t stream) {
    const float* x = (const float*)d_in[0];
    float* out = (float*)d_out;
    long long n4 = (long long)in_sizes[0] / 4;   // 31,457,280 granules

    // 2048 blocks x 15 grid-strided steps = 30,720 steps exactly; zero tail.
    copy_bulk<<<2048, 256, 0, stream>>>((const f4*)x, (f4*)out, n4);

    int bc = (int)((long long)in_sizes[0] / BC_STRIDE);  // 128
    int total = bc * CHARTS;                              // 640
    pole_fix<<<(total + 127) / 128, 128, 0, stream>>>(x, out, total);
}

// Round 8
// 195.875 us; speedup vs baseline: 1.0757x; 1.0757x over previous
//
#include <hip/hip_runtime.h>

// Geometry fixed by the reference: x [B=2, C=64, R_rot=6, charts=5, H=128, W=256] fp32.
#define RROT   6
#define CHARTS 5
#define CHART_STRIDE 32768LL                 // H*W = 128*256 elements
#define ROT_STRIDE   163840LL                // 5*CHART_STRIDE
#define BC_STRIDE    983040LL                // 6*ROT_STRIDE
// Granule (float4) strides
#define CHART_G (CHART_STRIDE / 4)           // 8192
#define ROT_G   (ROT_STRIDE / 4)             // 40960
#define BC_G    (BC_STRIDE / 4)              // 245760

typedef float f4 __attribute__((ext_vector_type(4)));

// One kernel, two roles split by blockIdx:
//  - blocks [0, copy_blocks): R4's NT pipelined grid-strided copy, except the
//    two pole granules per chart (chart-granule-offsets 0 and 32) are NOT
//    written (store-side exec-mask skip: no extra loads, no waitcnt drain).
//  - blocks [copy_blocks, ...): 640 threads total; each (bc, chart) computes
//    both pole means from the input and writes the 12 skipped granules
//    entirely (elem 0 = mean, elems 1..3 copied from input).
// Write sets are disjoint -> no race, no ordering needed, single dispatch.
__global__ __launch_bounds__(256) void smooth_all(
        const f4* __restrict__ in, f4* __restrict__ out,
        long long n4, const float* __restrict__ x,
        int copy_blocks, int total_pairs) {
    const int t = threadIdx.x;

    if ((int)blockIdx.x >= copy_blocks) {
        // ---- pole-fix role ----
        int idx = ((int)blockIdx.x - copy_blocks) * 256 + t;
        if (idx >= total_pairs) return;
        int c  = idx % CHARTS;
        long long bc = idx / CHARTS;
        int cm = (c + CHARTS - 1) % CHARTS;
        const float* base = x + bc * BC_STRIDE;

        float s1 = 0.0f, s2 = 0.0f;
        #pragma unroll
        for (int r = 0; r < RROT; ++r) {
            const float* rb = base + r * ROT_STRIDE;
            // V1 of pole (0,0): [c,1,0],[c,1,1],[c,0,1],[cm,127,128],[cm,127,127]
            s1 += rb[c  * CHART_STRIDE + 256]
                + rb[c  * CHART_STRIDE + 257]
                + rb[c  * CHART_STRIDE + 1]
                + rb[cm * CHART_STRIDE + 32640]
                + rb[cm * CHART_STRIDE + 32639];
            // V2 of pole (0,128): [c,1,128],[c,1,129],[c,0,129],[cm,127,255],[c,0,127]
            s2 += rb[c  * CHART_STRIDE + 384]
                + rb[c  * CHART_STRIDE + 385]
                + rb[c  * CHART_STRIDE + 129]
                + rb[cm * CHART_STRIDE + 32767]
                + rb[c  * CHART_STRIDE + 127];
        }
        float m1 = s1 * (1.0f / 30.0f);
        float m2 = s2 * (1.0f / 30.0f);

        long long gbase = bc * BC_G + (long long)c * CHART_G;
        #pragma unroll
        for (int r = 0; r < RROT; ++r) {
            long long g1 = gbase + (long long)r * ROT_G;  // pole1 granule (cols 0..3)
            long long g2 = g1 + 32;                        // pole2 granule (cols 128..131)
            f4 v1 = in[g1]; v1.x = m1;
            f4 v2 = in[g2]; v2.x = m2;
            out[g1] = v1;
            out[g2] = v2;
        }
        return;
    }

    // ---- streaming-copy role (R4 structure, NT, grid-strided) ----
    const long long n_steps = n4 >> 10;               // granules / 1024
    const long long G = copy_blocks;
    long long s = blockIdx.x;
    if (s < n_steps) {
        long long b = (s << 10) + t;
        f4 a0 = __builtin_nontemporal_load(&in[b]);
        f4 a1 = __builtin_nontemporal_load(&in[b + 256]);
        f4 a2 = __builtin_nontemporal_load(&in[b + 512]);
        f4 a3 = __builtin_nontemporal_load(&in[b + 768]);
        for (;;) {
            // Pole granules sit at chart-granule-offsets 0 and 32; charts are
            // 8192 granules = 8 steps, so only steps s%8==0, lanes 0 and 32,
            // first store. Skip that store; fix blocks own those granules.
            bool skip = ((s & 7) == 0) & ((t == 0) | (t == 32));
            long long s2 = s + G;
            if (s2 < n_steps) {
                long long b2 = (s2 << 10) + t;
                f4 c0 = __builtin_nontemporal_load(&in[b2]);
                f4 c1 = __builtin_nontemporal_load(&in[b2 + 256]);
                f4 c2 = __builtin_nontemporal_load(&in[b2 + 512]);
                f4 c3 = __builtin_nontemporal_load(&in[b2 + 768]);
                if (!skip) __builtin_nontemporal_store(a0, &out[b]);
                __builtin_nontemporal_store(a1, &out[b + 256]);
                __builtin_nontemporal_store(a2, &out[b + 512]);
                __builtin_nontemporal_store(a3, &out[b + 768]);
                a0 = c0; a1 = c1; a2 = c2; a3 = c3;
                s = s2; b = b2;
            } else {
                if (!skip) __builtin_nontemporal_store(a0, &out[b]);
                __builtin_nontemporal_store(a1, &out[b + 256]);
                __builtin_nontemporal_store(a2, &out[b + 512]);
                __builtin_nontemporal_store(a3, &out[b + 768]);
                break;
            }
        }
    }
    // Tail (n4 % 1024) — empty for this shape, kept for safety. Pole granules
    // never land here (they sit at chart starts, multiples of 8192).
    long long tail = n_steps << 10;
    long long stride = G * blockDim.x;
    for (long long g = tail + (long long)blockIdx.x * blockDim.x + t; g < n4; g += stride)
        out[g] = in[g];
}

extern "C" void kernel_launch(void* const* d_in, const int* in_sizes, int n_in,
                              void* d_out, int out_size, void* d_ws, size_t ws_size,
                              hipStream_t stream) {
    const float* x = (const float*)d_in[0];
    float* out = (float*)d_out;
    long long n4 = (long long)in_sizes[0] / 4;   // 31,457,280 granules

    int copy_blocks = 2048;                       // 15 grid-strided steps each, zero tail
    int bc = (int)((long long)in_sizes[0] / BC_STRIDE);  // 128
    int total_pairs = bc * CHARTS;                // 640 (bc, chart) pairs
    int fix_blocks = (total_pairs + 255) / 256;   // 3

    smooth_all<<<copy_blocks + fix_blocks, 256, 0, stream>>>(
        (const f4*)x, (f4*)out, n4, x, copy_blocks, total_pairs);
}